// Round 1
// baseline (713.061 us; speedup 1.0000x reference)
//
#include <hip/hip_runtime.h>
#include <math.h>

// ---------------------------------------------------------------------------
// GriffinRecurrentBlock: x1=x@Wx+bx ; x2=causal_conv4(x1)+cb ;
// gx=sig(x2@Gi+gib) ; ga=sig(x2@Ga+gab) ; a=exp(-8*ga*softplus(ap)) (a[t0]=0)
// mult=sqrt(1-a^2) ; nx=gx*x2*mult ; h=scan(h=a*h+nx) ; y=gelu(x@Wy+by) ;
// out=h*y ; outputs (out, h, h[:,T-1,:])
//
// Pipeline: prep(transpose weights->fp16, bias concat, x->fp16)
//   GEMM1 (M=32768,N=2048,K=1024) fp16 MFMA -> [x1|u]
//   conv  -> x2 (fp16)
//   GEMM2 -> [gx|a]   (a computed in fp32 in epilogue)
//   gatefuse: nx = gx*x2*sqrt(1-a^2)   (in-place over x2)
//   chunked scan (128 chunks x 32): pass1 summaries, pass2 carries,
//   pass3 scan + gelu + out/h/hn writes.
// ---------------------------------------------------------------------------

#define B_ 8
#define T_ 4096
#define H_ 1024
#define M_ (B_ * T_)          // 32768
#define NC_ 128               // chunks per sequence
#define CL_ 32                // chunk length (T_/NC_)

typedef _Float16 half8 __attribute__((ext_vector_type(8)));
typedef _Float16 half4 __attribute__((ext_vector_type(4)));
typedef float    f32x4 __attribute__((ext_vector_type(4)));

// ---------------- prep: 32x32 LDS transpose + fp32->fp16 -------------------
// dst[n][k] = src[k][n] ; n in [0,2048) picks sA (n<1024) or sB.
__global__ __launch_bounds__(256) void transpose_cvt(
    const float* __restrict__ sA, const float* __restrict__ sB,
    _Float16* __restrict__ dst) {
  __shared__ float tile[32][33];
  int bn = blockIdx.x * 32;
  int bk = blockIdx.y * 32;
  const float* src = (bn < 1024) ? sA : sB;
  int nof = (bn < 1024) ? bn : bn - 1024;
  int c  = threadIdx.x & 31;
  int r0 = threadIdx.x >> 5;
#pragma unroll
  for (int i = 0; i < 4; ++i) {
    int r = r0 + i * 8;
    tile[r][c] = src[(size_t)(bk + r) * 1024 + nof + c];
  }
  __syncthreads();
#pragma unroll
  for (int i = 0; i < 4; ++i) {
    int nl = r0 + i * 8;
    dst[(size_t)(bn + nl) * 1024 + bk + c] = (_Float16)tile[c][nl];
  }
}

__global__ void prep_bias(const float* __restrict__ bx, const float* __restrict__ by,
                          const float* __restrict__ gib, const float* __restrict__ gab,
                          float* __restrict__ b1, float* __restrict__ b2) {
  int i = blockIdx.x * 1024 + threadIdx.x;   // 0..4095
  if (i < 1024)      b1[i] = bx[i];
  else if (i < 2048) b1[i] = by[i - 1024];
  else if (i < 3072) b2[i - 2048] = gib[i - 2048];
  else               b2[i - 2048] = gab[i - 3072];
}

__global__ __launch_bounds__(256) void cvt_fp16(
    const float* __restrict__ x, _Float16* __restrict__ xh, long n4) {
  for (long i = (long)blockIdx.x * 256 + threadIdx.x; i < n4;
       i += (long)gridDim.x * 256) {
    f32x4 v = ((const f32x4*)x)[i];
    half4 h;
#pragma unroll
    for (int e = 0; e < 4; ++e) h[e] = (_Float16)v[e];
    ((half4*)xh)[i] = h;
  }
}

// ---------------- GEMM: C[M][2048] = A[M][1024] * Bt[2048][1024]^T ----------
// 128x128 tile, 4 waves (2x2 of 64x64), BK=32, v_mfma_f32_16x16x32_f16.
// LDS layout: slot(kg,row) = kg*128 + (row ^ kg); 16B frags, conflict-free.
// MODE 0: store v+bias (fp16).  MODE 1: n<1024 -> sigmoid; n>=1024 -> a.
template <int MODE>
__global__ __launch_bounds__(256) void gemm_kernel(
    const _Float16* __restrict__ A, const _Float16* __restrict__ Bt,
    const float* __restrict__ bias, const float* __restrict__ a_param,
    _Float16* __restrict__ C) {
  __shared__ half8 AsV[512];
  __shared__ half8 BsV[512];
  const int K = 1024;
  int tid  = threadIdx.x;
  int lane = tid & 63;
  int wave = tid >> 6;
  int mtile = blockIdx.x >> 4;          // 256 m-tiles
  int ntile = blockIdx.x & 15;          // 16 n-tiles (n-fast: A-panel L2 reuse)
  int m0 = mtile * 128, n0 = ntile * 128;
  int wm = wave >> 1, wn = wave & 1;

  // staging: lane -> (row=tid>>2, kg=tid&3); rows srow and srow+64.
  int srow = tid >> 2;
  int skg  = tid & 3;
  const half8* Ag8 = (const half8*)(A  + (size_t)(m0 + srow) * K + skg * 8);
  const half8* Bg8 = (const half8*)(Bt + (size_t)(n0 + srow) * K + skg * 8);
  int wslot = skg * 128 + (srow ^ skg);

  f32x4 acc[4][4];
  f32x4 zero = {0.f, 0.f, 0.f, 0.f};
#pragma unroll
  for (int i = 0; i < 4; ++i)
#pragma unroll
    for (int j = 0; j < 4; ++j) acc[i][j] = zero;

  int g  = lane >> 4;
  int fa = g * 128 + wm * 64 + ((lane & 15) ^ g);
  int fb = g * 128 + wn * 64 + ((lane & 15) ^ g);

  half8 pa0 = Ag8[0], pa1 = Ag8[8192];    // 64 rows * 1024 halfs = 8192 half8
  half8 pb0 = Bg8[0], pb1 = Bg8[8192];

  for (int kk = 0; kk < 32; ++kk) {
    AsV[wslot]      = pa0;
    AsV[wslot + 64] = pa1;
    BsV[wslot]      = pb0;
    BsV[wslot + 64] = pb1;
    __syncthreads();
    if (kk < 31) {                         // prefetch next K-step
      pa0 = Ag8[(kk + 1) * 4];
      pa1 = Ag8[(kk + 1) * 4 + 8192];
      pb0 = Bg8[(kk + 1) * 4];
      pb1 = Bg8[(kk + 1) * 4 + 8192];
    }
    half8 af[4], bf[4];
#pragma unroll
    for (int mi = 0; mi < 4; ++mi) af[mi] = AsV[fa + mi * 16];
#pragma unroll
    for (int ni = 0; ni < 4; ++ni) bf[ni] = BsV[fb + ni * 16];
#pragma unroll
    for (int mi = 0; mi < 4; ++mi)
#pragma unroll
      for (int ni = 0; ni < 4; ++ni)
        acc[mi][ni] = __builtin_amdgcn_mfma_f32_16x16x32_f16(
            af[mi], bf[ni], acc[mi][ni], 0, 0, 0);
    __syncthreads();
  }

  // epilogue: C/D layout col=lane&15, row=(lane>>4)*4+p  (HW-verified)
  int lr = lane >> 4;
  int lc = lane & 15;
#pragma unroll
  for (int ni = 0; ni < 4; ++ni) {
    int gn = n0 + wn * 64 + ni * 16 + lc;
    float bs = bias[gn];
    float sp = 0.f;
    if (MODE == 1 && gn >= 1024) {
      float apv = a_param[gn - 1024];
      sp = log1pf(expf(apv));              // softplus, exact for ap in [2,6]
    }
#pragma unroll
    for (int mi = 0; mi < 4; ++mi) {
      int gmb = m0 + wm * 64 + mi * 16 + lr * 4;
#pragma unroll
      for (int p = 0; p < 4; ++p) {
        float v = acc[mi][ni][p] + bs;
        if (MODE == 1) {
          float s = 1.f / (1.f + expf(-v));
          if (gn < 1024) {
            v = s;                         // gate_x
          } else {
            float a = expf(-8.f * s * sp); // fp32 'a' before fp16 store
            if (((gmb + p) & (T_ - 1)) == 0) a = 0.f;  // t == 0
            v = a;
          }
        }
        C[(size_t)(gmb + p) * 2048 + gn] = (_Float16)v;
      }
    }
  }
}

// ---------------- conv: x2 = sum_j cw[3-j]*x1[t-j] + cb ---------------------
__global__ __launch_bounds__(256) void conv_kernel(
    const _Float16* __restrict__ g1, const float* __restrict__ cw,
    const float* __restrict__ cb, _Float16* __restrict__ x2) {
  int idx = blockIdx.x * 256 + threadIdx.x;   // over M_*H_/8
  int m  = idx >> 7;
  int hb = (idx & 127) * 8;
  int t  = m & (T_ - 1);
  float acc[8];
#pragma unroll
  for (int e = 0; e < 8; ++e) acc[e] = cb[hb + e];
#pragma unroll
  for (int j = 0; j < 4; ++j) {
    if (t >= j) {
      half8 xv = *(const half8*)&g1[(size_t)(m - j) * 2048 + hb];
      const float* w = &cw[(3 - j) * 1024 + hb];
#pragma unroll
      for (int e = 0; e < 8; ++e) acc[e] += w[e] * (float)xv[e];
    }
  }
  half8 o;
#pragma unroll
  for (int e = 0; e < 8; ++e) o[e] = (_Float16)acc[e];
  *(half8*)&x2[(size_t)m * 1024 + hb] = o;
}

// ---------------- gatefuse: nx = gx * x2 * sqrt(1-a^2) (in-place x2) --------
__global__ __launch_bounds__(256) void gatefuse_kernel(
    const _Float16* __restrict__ g2, _Float16* __restrict__ x2) {
  int idx = blockIdx.x * 256 + threadIdx.x;
  int m  = idx >> 7;
  int hb = (idx & 127) * 8;
  half8 gx = *(const half8*)&g2[(size_t)m * 2048 + hb];
  half8 av = *(const half8*)&g2[(size_t)m * 2048 + 1024 + hb];
  half8 xv = *(const half8*)&x2[(size_t)m * 1024 + hb];
  half8 o;
#pragma unroll
  for (int e = 0; e < 8; ++e) {
    float a = (float)av[e];
    float mult = sqrtf(fmaxf(1.f - a * a, 0.f));   // == sqrt(1-exp(2 log a))
    o[e] = (_Float16)((float)gx[e] * (float)xv[e] * mult);
  }
  *(half8*)&x2[(size_t)m * 1024 + hb] = o;
}

// ---------------- scan pass 1: per-chunk (prod a, local h) ------------------
__global__ __launch_bounds__(128) void scan1_kernel(
    const _Float16* __restrict__ g2, const _Float16* __restrict__ nx,
    float* __restrict__ cA, float* __restrict__ cH) {
  int bid = blockIdx.x;          // b*NC_ + c
  int b = bid >> 7, c = bid & 127;
  int h0 = threadIdx.x * 8;
  float A[8], Hh[8];
#pragma unroll
  for (int e = 0; e < 8; ++e) { A[e] = 1.f; Hh[e] = 0.f; }
  size_t mbase = (size_t)b * T_ + (size_t)c * CL_;
  for (int i = 0; i < CL_; ++i) {
    size_t m = mbase + i;
    half8 av = *(const half8*)&g2[m * 2048 + 1024 + h0];
    half8 xv = *(const half8*)&nx[m * 1024 + h0];
#pragma unroll
    for (int e = 0; e < 8; ++e) {
      float a = (float)av[e];
      A[e] *= a;
      Hh[e] = (float)xv[e] + a * Hh[e];
    }
  }
  size_t o = (size_t)bid * 1024 + h0;
#pragma unroll
  for (int e = 0; e < 8; ++e) { cA[o + e] = A[e]; cH[o + e] = Hh[e]; }
}

// ---------------- scan pass 2: carries across chunks ------------------------
__global__ void scanmid_kernel(const float* __restrict__ cA,
                               const float* __restrict__ cH,
                               float* __restrict__ carry) {
  int gidx = blockIdx.x * 256 + threadIdx.x;  // 8192 = B_*H_
  int b = gidx >> 10, h = gidx & 1023;
  float run = 0.f;
  for (int c = 0; c < NC_; ++c) {
    size_t o = ((size_t)(b * NC_ + c)) * 1024 + h;
    carry[o] = run;
    run = cH[o] + cA[o] * run;
  }
}

// ---------------- scan pass 3: h, out = h*gelu(u), hn -----------------------
__global__ __launch_bounds__(128) void scan2_kernel(
    const _Float16* __restrict__ g2, const _Float16* __restrict__ nx,
    const _Float16* __restrict__ g1, const float* __restrict__ carry,
    float* __restrict__ outO, float* __restrict__ outH,
    float* __restrict__ outHn) {
  int bid = blockIdx.x;
  int b = bid >> 7, c = bid & 127;
  int h0 = threadIdx.x * 8;
  float Hh[8];
  {
    size_t o = (size_t)bid * 1024 + h0;
#pragma unroll
    for (int e = 0; e < 8; ++e) Hh[e] = carry[o + e];
  }
  size_t mbase = (size_t)b * T_ + (size_t)c * CL_;
  for (int i = 0; i < CL_; ++i) {
    size_t m = mbase + i;
    half8 av = *(const half8*)&g2[m * 2048 + 1024 + h0];
    half8 xv = *(const half8*)&nx[m * 1024 + h0];
    half8 uv = *(const half8*)&g1[m * 2048 + 1024 + h0];
    f32x4 hO[2], oO[2];
#pragma unroll
    for (int e = 0; e < 8; ++e) {
      float a = (float)av[e];
      float v = (float)xv[e] + a * Hh[e];
      Hh[e] = v;
      float u = (float)uv[e];
      float y = 0.5f * u * (1.f + erff(u * 0.70710678118654752f));  // exact gelu
      hO[e >> 2][e & 3] = v;
      oO[e >> 2][e & 3] = v * y;
    }
    size_t ob = m * 1024 + h0;
    *(f32x4*)&outH[ob]     = hO[0];
    *(f32x4*)&outH[ob + 4] = hO[1];
    *(f32x4*)&outO[ob]     = oO[0];
    *(f32x4*)&outO[ob + 4] = oO[1];
  }
  if (c == NC_ - 1) {
    size_t o = (size_t)b * 1024 + h0;
#pragma unroll
    for (int e = 0; e < 8; ++e) outHn[o + e] = Hh[e];
  }
}

// ---------------------------------------------------------------------------
extern "C" void kernel_launch(void* const* d_in, const int* in_sizes, int n_in,
                              void* d_out, int out_size, void* d_ws,
                              size_t ws_size, hipStream_t stream) {
  const float* x   = (const float*)d_in[0];
  const float* wx  = (const float*)d_in[1];
  const float* bx  = (const float*)d_in[2];
  const float* wy  = (const float*)d_in[3];
  const float* by  = (const float*)d_in[4];
  const float* cw  = (const float*)d_in[5];
  const float* cb  = (const float*)d_in[6];
  const float* giw = (const float*)d_in[7];
  const float* gib = (const float*)d_in[8];
  const float* gaw = (const float*)d_in[9];
  const float* gab = (const float*)d_in[10];
  const float* ap  = (const float*)d_in[11];

  char* ws = (char*)d_ws;
  size_t off = 0;
  auto alloc = [&](size_t bytes) {
    char* p = ws + off;
    off += (bytes + 255) & ~(size_t)255;
    return p;
  };
  _Float16* wT1 = (_Float16*)alloc((size_t)2048 * 1024 * 2);  // [n][k] fp16
  _Float16* wT2 = (_Float16*)alloc((size_t)2048 * 1024 * 2);
  float*    b1  = (float*)alloc(2048 * 4);
  float*    b2  = (float*)alloc(2048 * 4);
  _Float16* xh  = (_Float16*)alloc((size_t)M_ * 1024 * 2);  // x fp16; aliased
  _Float16* g2e = (_Float16*)alloc((size_t)M_ * 1024 * 2);  // extension
  (void)g2e;
  _Float16* g1o = (_Float16*)alloc((size_t)M_ * 2048 * 2);  // [x1 | u]
  _Float16* x2h = (_Float16*)alloc((size_t)M_ * 1024 * 2);  // x2 -> nx
  float* cA  = (float*)alloc((size_t)B_ * NC_ * 1024 * 4);
  float* cH  = (float*)alloc((size_t)B_ * NC_ * 1024 * 4);
  float* cin = (float*)alloc((size_t)B_ * NC_ * 1024 * 4);
  _Float16* g2o = xh;  // [gx | a], 134MB spanning xh+g2e (xh dead by then)

  float* oO  = (float*)d_out;
  float* oH  = oO + (size_t)M_ * 1024;
  float* oHn = oO + (size_t)2 * M_ * 1024;

  transpose_cvt<<<dim3(64, 32), 256, 0, stream>>>(wx, wy, wT1);
  transpose_cvt<<<dim3(64, 32), 256, 0, stream>>>(giw, gaw, wT2);
  prep_bias<<<4, 1024, 0, stream>>>(bx, by, gib, gab, b1, b2);
  cvt_fp16<<<2048, 256, 0, stream>>>(x, xh, (long)M_ * 1024 / 4);

  gemm_kernel<0><<<4096, 256, 0, stream>>>(xh, wT1, b1, nullptr, g1o);
  conv_kernel<<<16384, 256, 0, stream>>>(g1o, cw, cb, x2h);
  gemm_kernel<1><<<4096, 256, 0, stream>>>(x2h, wT2, b2, ap, g2o);
  gatefuse_kernel<<<16384, 256, 0, stream>>>(g2o, x2h);

  scan1_kernel<<<B_ * NC_, 128, 0, stream>>>(g2o, x2h, cA, cH);
  scanmid_kernel<<<32, 256, 0, stream>>>(cA, cH, cin);
  scan2_kernel<<<B_ * NC_, 128, 0, stream>>>(g2o, x2h, g1o, cin, oO, oH, oHn);
}

// Round 2
// 638.509 us; speedup vs baseline: 1.1168x; 1.1168x over previous
//
#include <hip/hip_runtime.h>
#include <math.h>

// ---------------------------------------------------------------------------
// GriffinRecurrentBlock: x1=x@Wx+bx ; x2=causal_conv4(x1)+cb ;
// gx=sig(x2@Gi+gib) ; ga=sig(x2@Ga+gab) ; a=exp(-8*ga*softplus(ap)) (a[t0]=0)
// mult=sqrt(1-a^2) ; nx=gx*x2*mult ; h=scan(h=a*h+nx) ; y=gelu(x@Wy+by) ;
// out=h*y ; outputs (out, h, h[:,T-1,:])
//
// R1 changes: GEMM staging via global_load_lds dwordx4 (m97 pattern, linear
// LDS), XCD-bijective block swizzle, row-grouped epilogue stores, gatefuse
// folded into scan1/scan2 (nx recomputed from gx,a,x2 in fp32).
// ---------------------------------------------------------------------------

#define B_ 8
#define T_ 4096
#define H_ 1024
#define M_ (B_ * T_)          // 32768
#define NC_ 128               // chunks per sequence
#define CL_ 32                // chunk length (T_/NC_)

typedef _Float16 half8 __attribute__((ext_vector_type(8)));
typedef _Float16 half4 __attribute__((ext_vector_type(4)));
typedef float    f32x4 __attribute__((ext_vector_type(4)));

__device__ __forceinline__ void load16_lds(const _Float16* g, _Float16* l) {
  __builtin_amdgcn_global_load_lds(
      (const __attribute__((address_space(1))) void*)g,
      (__attribute__((address_space(3))) void*)l, 16, 0, 0);
}

// ---------------- prep: 32x32 LDS transpose + fp32->fp16 -------------------
__global__ __launch_bounds__(256) void transpose_cvt(
    const float* __restrict__ sA, const float* __restrict__ sB,
    _Float16* __restrict__ dst) {
  __shared__ float tile[32][33];
  int bn = blockIdx.x * 32;
  int bk = blockIdx.y * 32;
  const float* src = (bn < 1024) ? sA : sB;
  int nof = (bn < 1024) ? bn : bn - 1024;
  int c  = threadIdx.x & 31;
  int r0 = threadIdx.x >> 5;
#pragma unroll
  for (int i = 0; i < 4; ++i) {
    int r = r0 + i * 8;
    tile[r][c] = src[(size_t)(bk + r) * 1024 + nof + c];
  }
  __syncthreads();
#pragma unroll
  for (int i = 0; i < 4; ++i) {
    int nl = r0 + i * 8;
    dst[(size_t)(bn + nl) * 1024 + bk + c] = (_Float16)tile[c][nl];
  }
}

__global__ void prep_bias(const float* __restrict__ bx, const float* __restrict__ by,
                          const float* __restrict__ gib, const float* __restrict__ gab,
                          float* __restrict__ b1, float* __restrict__ b2) {
  int i = blockIdx.x * 1024 + threadIdx.x;   // 0..4095
  if (i < 1024)      b1[i] = bx[i];
  else if (i < 2048) b1[i] = by[i - 1024];
  else if (i < 3072) b2[i - 2048] = gib[i - 2048];
  else               b2[i - 2048] = gab[i - 3072];
}

__global__ __launch_bounds__(256) void cvt_fp16(
    const float* __restrict__ x, _Float16* __restrict__ xh, long n4) {
  for (long i = (long)blockIdx.x * 256 + threadIdx.x; i < n4;
       i += (long)gridDim.x * 256) {
    f32x4 v = ((const f32x4*)x)[i];
    half4 h;
#pragma unroll
    for (int e = 0; e < 4; ++e) h[e] = (_Float16)v[e];
    ((half4*)xh)[i] = h;
  }
}

// ---------------- GEMM: C[M][2048] = A[M][1024] * Bt[2048][1024]^T ----------
// 128x128 tile, 4 waves (2x2 of 64x64), BK=32, v_mfma_f32_16x16x32_f16.
// Staging: global_load_lds dwordx4, linear LDS [row][32 halfs] (m97 pattern).
// MODE 0: store v+bias (fp16).  MODE 1: n<1024 -> sigmoid; n>=1024 -> a.
template <int MODE>
__global__ __launch_bounds__(256, 2) void gemm_kernel(
    const _Float16* __restrict__ A, const _Float16* __restrict__ Bt,
    const float* __restrict__ bias, const float* __restrict__ a_param,
    _Float16* __restrict__ C) {
  __shared__ _Float16 sA[128 * 32];   // 8 KB
  __shared__ _Float16 sB[128 * 32];   // 8 KB
  const int K = 1024;
  int tid  = threadIdx.x;
  int lane = tid & 63;
  int wave = tid >> 6;

  // XCD-bijective swizzle: gridDim.x divisible by 8; XCD x gets a contiguous
  // range of logical blocks -> A-panel reuse within each XCD's L2.
  int nb  = (int)blockIdx.x;
  int per = (int)gridDim.x >> 3;
  nb = (nb & 7) * per + (nb >> 3);
  int mtile = nb >> 4;                  // 256 m-tiles
  int ntile = nb & 15;                  // 16 n-tiles (n-fast: A-panel reuse)
  int m0 = mtile * 128, n0 = ntile * 128;
  int wm = wave >> 1, wn = wave & 1;

  // staging chunk for issue j: c = j*256 + tid ; row = c>>2, kg = c&3
  int row0 = tid >> 2, kg0 = tid & 3;
  const _Float16* gA0 = A  + (size_t)(m0 + row0) * K + kg0 * 8;
  const _Float16* gA1 = gA0 + (size_t)64 * K;
  const _Float16* gB0 = Bt + (size_t)(n0 + row0) * K + kg0 * 8;
  const _Float16* gB1 = gB0 + (size_t)64 * K;
  // per-wave LDS dest base (HW adds lane*16 bytes): (j*256 + wave*64)*8 halfs
  _Float16* lA0 = sA + wave * 512;
  _Float16* lA1 = sA + 2048 + wave * 512;
  _Float16* lB0 = sB + wave * 512;
  _Float16* lB1 = sB + 2048 + wave * 512;

  f32x4 acc[4][4];
  f32x4 zero = {0.f, 0.f, 0.f, 0.f};
#pragma unroll
  for (int i = 0; i < 4; ++i)
#pragma unroll
    for (int j = 0; j < 4; ++j) acc[i][j] = zero;

  const half8* sA8 = (const half8*)sA;
  const half8* sB8 = (const half8*)sB;
  // fragment: lane l -> row (l&15), k-group (l>>4); row stride = 4 half8
  int fa = (wm * 64 + (lane & 15)) * 4 + (lane >> 4);
  int fb = (wn * 64 + (lane & 15)) * 4 + (lane >> 4);

  for (int kk = 0; kk < 32; ++kk) {
    int ko = kk * 32;
    load16_lds(gA0 + ko, lA0);
    load16_lds(gA1 + ko, lA1);
    load16_lds(gB0 + ko, lB0);
    load16_lds(gB1 + ko, lB1);
    __syncthreads();                      // drains vmcnt, publishes LDS
    half8 af[4], bf[4];
#pragma unroll
    for (int mi = 0; mi < 4; ++mi) af[mi] = sA8[fa + mi * 64];
#pragma unroll
    for (int ni = 0; ni < 4; ++ni) bf[ni] = sB8[fb + ni * 64];
#pragma unroll
    for (int mi = 0; mi < 4; ++mi)
#pragma unroll
      for (int ni = 0; ni < 4; ++ni)
        acc[mi][ni] = __builtin_amdgcn_mfma_f32_16x16x32_f16(
            af[mi], bf[ni], acc[mi][ni], 0, 0, 0);
    __syncthreads();                      // compute done before next stage
  }

  // epilogue: C/D layout col=lane&15, row=(lane>>4)*4+p  (HW-verified)
  int lr = lane >> 4;
  int lc = lane & 15;
  int   gn[4];
  float bs[4], sp[4];
#pragma unroll
  for (int ni = 0; ni < 4; ++ni) {
    gn[ni] = n0 + wn * 64 + ni * 16 + lc;
    bs[ni] = bias[gn[ni]];
    sp[ni] = 0.f;
    if (MODE == 1 && gn[ni] >= 1024)
      sp[ni] = log1pf(expf(a_param[gn[ni] - 1024]));   // softplus
  }
#pragma unroll
  for (int mi = 0; mi < 4; ++mi) {
#pragma unroll
    for (int p = 0; p < 4; ++p) {
      int gm = m0 + wm * 64 + mi * 16 + lr * 4 + p;
      size_t rowb = (size_t)gm * 2048;
#pragma unroll
      for (int ni = 0; ni < 4; ++ni) {    // 4 stores to one row, consecutive
        float v = acc[mi][ni][p] + bs[ni];
        if (MODE == 1) {
          float s = 1.f / (1.f + expf(-v));
          if (gn[ni] < 1024) {
            v = s;                         // gate_x (sigmoided)
          } else {
            float a = expf(-8.f * s * sp[ni]);
            if ((gm & (T_ - 1)) == 0) a = 0.f;   // t == 0
            v = a;
          }
        }
        C[rowb + gn[ni]] = (_Float16)v;
      }
    }
  }
}

// ---------------- conv: x2 = sum_j cw[3-j]*x1[t-j] + cb ---------------------
__global__ __launch_bounds__(256) void conv_kernel(
    const _Float16* __restrict__ g1, const float* __restrict__ cw,
    const float* __restrict__ cb, _Float16* __restrict__ x2) {
  int idx = blockIdx.x * 256 + threadIdx.x;   // over M_*H_/8
  int m  = idx >> 7;
  int hb = (idx & 127) * 8;
  int t  = m & (T_ - 1);
  float acc[8];
#pragma unroll
  for (int e = 0; e < 8; ++e) acc[e] = cb[hb + e];
#pragma unroll
  for (int j = 0; j < 4; ++j) {
    if (t >= j) {
      half8 xv = *(const half8*)&g1[(size_t)(m - j) * 2048 + hb];
      const float* w = &cw[(3 - j) * 1024 + hb];
#pragma unroll
      for (int e = 0; e < 8; ++e) acc[e] += w[e] * (float)xv[e];
    }
  }
  half8 o;
#pragma unroll
  for (int e = 0; e < 8; ++e) o[e] = (_Float16)acc[e];
  *(half8*)&x2[(size_t)m * 1024 + hb] = o;
}

// ---------------- scan pass 1: per-chunk (prod a, local h) ------------------
// nx = gx * x2 * sqrt(1-a^2) computed inline (gatefuse fused away).
__global__ __launch_bounds__(128) void scan1_kernel(
    const _Float16* __restrict__ g2, const _Float16* __restrict__ x2,
    float* __restrict__ cA, float* __restrict__ cH) {
  int bid = blockIdx.x;          // b*NC_ + c
  int b = bid >> 7, c = bid & 127;
  int h0 = threadIdx.x * 8;
  float A[8], Hh[8];
#pragma unroll
  for (int e = 0; e < 8; ++e) { A[e] = 1.f; Hh[e] = 0.f; }
  size_t mbase = (size_t)b * T_ + (size_t)c * CL_;
  for (int i = 0; i < CL_; ++i) {
    size_t m = mbase + i;
    half8 gx = *(const half8*)&g2[m * 2048 + h0];
    half8 av = *(const half8*)&g2[m * 2048 + 1024 + h0];
    half8 xv = *(const half8*)&x2[m * 1024 + h0];
#pragma unroll
    for (int e = 0; e < 8; ++e) {
      float a = (float)av[e];
      float mult = sqrtf(fmaxf(1.f - a * a, 0.f));
      float nx = (float)gx[e] * (float)xv[e] * mult;
      A[e] *= a;
      Hh[e] = nx + a * Hh[e];
    }
  }
  size_t o = (size_t)bid * 1024 + h0;
#pragma unroll
  for (int e = 0; e < 8; ++e) { cA[o + e] = A[e]; cH[o + e] = Hh[e]; }
}

// ---------------- scan pass 2: carries across chunks ------------------------
__global__ void scanmid_kernel(const float* __restrict__ cA,
                               const float* __restrict__ cH,
                               float* __restrict__ carry) {
  int gidx = blockIdx.x * 256 + threadIdx.x;  // 8192 = B_*H_
  int b = gidx >> 10, h = gidx & 1023;
  float run = 0.f;
  for (int c = 0; c < NC_; ++c) {
    size_t o = ((size_t)(b * NC_ + c)) * 1024 + h;
    carry[o] = run;
    run = cH[o] + cA[o] * run;
  }
}

// ---------------- scan pass 3: h, out = h*gelu(u), hn -----------------------
__global__ __launch_bounds__(128) void scan2_kernel(
    const _Float16* __restrict__ g2, const _Float16* __restrict__ x2,
    const _Float16* __restrict__ g1, const float* __restrict__ carry,
    float* __restrict__ outO, float* __restrict__ outH,
    float* __restrict__ outHn) {
  int bid = blockIdx.x;
  int b = bid >> 7, c = bid & 127;
  int h0 = threadIdx.x * 8;
  float Hh[8];
  {
    size_t o = (size_t)bid * 1024 + h0;
#pragma unroll
    for (int e = 0; e < 8; ++e) Hh[e] = carry[o + e];
  }
  size_t mbase = (size_t)b * T_ + (size_t)c * CL_;
  for (int i = 0; i < CL_; ++i) {
    size_t m = mbase + i;
    half8 gx = *(const half8*)&g2[m * 2048 + h0];
    half8 av = *(const half8*)&g2[m * 2048 + 1024 + h0];
    half8 xv = *(const half8*)&x2[m * 1024 + h0];
    half8 uv = *(const half8*)&g1[m * 2048 + 1024 + h0];
    f32x4 hO[2], oO[2];
#pragma unroll
    for (int e = 0; e < 8; ++e) {
      float a = (float)av[e];
      float mult = sqrtf(fmaxf(1.f - a * a, 0.f));
      float nx = (float)gx[e] * (float)xv[e] * mult;
      float v = nx + a * Hh[e];
      Hh[e] = v;
      float u = (float)uv[e];
      float y = 0.5f * u * (1.f + erff(u * 0.70710678118654752f));  // exact gelu
      hO[e >> 2][e & 3] = v;
      oO[e >> 2][e & 3] = v * y;
    }
    size_t ob = m * 1024 + h0;
    *(f32x4*)&outH[ob]     = hO[0];
    *(f32x4*)&outH[ob + 4] = hO[1];
    *(f32x4*)&outO[ob]     = oO[0];
    *(f32x4*)&outO[ob + 4] = oO[1];
  }
  if (c == NC_ - 1) {
    size_t o = (size_t)b * 1024 + h0;
#pragma unroll
    for (int e = 0; e < 8; ++e) outHn[o + e] = Hh[e];
  }
}

// ---------------------------------------------------------------------------
extern "C" void kernel_launch(void* const* d_in, const int* in_sizes, int n_in,
                              void* d_out, int out_size, void* d_ws,
                              size_t ws_size, hipStream_t stream) {
  const float* x   = (const float*)d_in[0];
  const float* wx  = (const float*)d_in[1];
  const float* bx  = (const float*)d_in[2];
  const float* wy  = (const float*)d_in[3];
  const float* by  = (const float*)d_in[4];
  const float* cw  = (const float*)d_in[5];
  const float* cb  = (const float*)d_in[6];
  const float* giw = (const float*)d_in[7];
  const float* gib = (const float*)d_in[8];
  const float* gaw = (const float*)d_in[9];
  const float* gab = (const float*)d_in[10];
  const float* ap  = (const float*)d_in[11];

  char* ws = (char*)d_ws;
  size_t off = 0;
  auto alloc = [&](size_t bytes) {
    char* p = ws + off;
    off += (bytes + 255) & ~(size_t)255;
    return p;
  };
  _Float16* wT1 = (_Float16*)alloc((size_t)2048 * 1024 * 2);  // [n][k] fp16
  _Float16* wT2 = (_Float16*)alloc((size_t)2048 * 1024 * 2);
  float*    b1  = (float*)alloc(2048 * 4);
  float*    b2  = (float*)alloc(2048 * 4);
  _Float16* xh  = (_Float16*)alloc((size_t)M_ * 1024 * 2);  // x fp16; aliased
  _Float16* g2e = (_Float16*)alloc((size_t)M_ * 1024 * 2);  // extension
  (void)g2e;
  _Float16* g1o = (_Float16*)alloc((size_t)M_ * 2048 * 2);  // [x1 | u]
  _Float16* x2h = (_Float16*)alloc((size_t)M_ * 1024 * 2);  // x2
  float* cA  = (float*)alloc((size_t)B_ * NC_ * 1024 * 4);
  float* cH  = (float*)alloc((size_t)B_ * NC_ * 1024 * 4);
  float* cin = (float*)alloc((size_t)B_ * NC_ * 1024 * 4);
  _Float16* g2o = xh;  // [gx | a], 134MB spanning xh+g2e (xh dead by then)

  float* oO  = (float*)d_out;
  float* oH  = oO + (size_t)M_ * 1024;
  float* oHn = oO + (size_t)2 * M_ * 1024;

  transpose_cvt<<<dim3(64, 32), 256, 0, stream>>>(wx, wy, wT1);
  transpose_cvt<<<dim3(64, 32), 256, 0, stream>>>(giw, gaw, wT2);
  prep_bias<<<4, 1024, 0, stream>>>(bx, by, gib, gab, b1, b2);
  cvt_fp16<<<2048, 256, 0, stream>>>(x, xh, (long)M_ * 1024 / 4);

  gemm_kernel<0><<<4096, 256, 0, stream>>>(xh, wT1, b1, nullptr, g1o);
  conv_kernel<<<16384, 256, 0, stream>>>(g1o, cw, cb, x2h);
  gemm_kernel<1><<<4096, 256, 0, stream>>>(x2h, wT2, b2, ap, g2o);

  scan1_kernel<<<B_ * NC_, 128, 0, stream>>>(g2o, x2h, cA, cH);
  scanmid_kernel<<<32, 256, 0, stream>>>(cA, cH, cin);
  scan2_kernel<<<B_ * NC_, 128, 0, stream>>>(g2o, x2h, g1o, cin, oO, oH, oHn);
}

// Round 3
// 619.962 us; speedup vs baseline: 1.1502x; 1.0299x over previous
//
#include <hip/hip_runtime.h>
#include <math.h>

// ---------------------------------------------------------------------------
// GriffinRecurrentBlock. R3: GEMM rewritten as 256x256 8-wave 8-phase
// (4 phases/K-tile) template: BK=64, dbuf LDS 128KB, XOR-swizzled rows,
// global_load_lds staging issued 2.5 phases ahead of the single vmcnt(0)
// per K-tile, setprio(1) around MFMA clusters (T2+T3+T4+T5).
// ---------------------------------------------------------------------------

#define B_ 8
#define T_ 4096
#define H_ 1024
#define M_ (B_ * T_)          // 32768
#define NC_ 128               // chunks per sequence
#define CL_ 32                // chunk length (T_/NC_)

typedef _Float16 half8 __attribute__((ext_vector_type(8)));
typedef _Float16 half4 __attribute__((ext_vector_type(4)));
typedef float    f32x4 __attribute__((ext_vector_type(4)));

#define FENCE asm volatile("" ::: "memory")
#define BAR() do { FENCE; __builtin_amdgcn_s_barrier(); FENCE; } while (0)
#define MFMA16(a, b, c) __builtin_amdgcn_mfma_f32_16x16x32_f16((a), (b), (c), 0, 0, 0)

__device__ __forceinline__ void load16_lds(const _Float16* g, _Float16* l) {
  __builtin_amdgcn_global_load_lds(
      (const __attribute__((address_space(1))) void*)g,
      (__attribute__((address_space(3))) void*)l, 16, 0, 0);
}

// ---------------- prep: 32x32 LDS transpose + fp32->fp16 -------------------
__global__ __launch_bounds__(256) void transpose_cvt(
    const float* __restrict__ sA, const float* __restrict__ sB,
    _Float16* __restrict__ dst) {
  __shared__ float tile[32][33];
  int bn = blockIdx.x * 32;
  int bk = blockIdx.y * 32;
  const float* src = (bn < 1024) ? sA : sB;
  int nof = (bn < 1024) ? bn : bn - 1024;
  int c  = threadIdx.x & 31;
  int r0 = threadIdx.x >> 5;
#pragma unroll
  for (int i = 0; i < 4; ++i) {
    int r = r0 + i * 8;
    tile[r][c] = src[(size_t)(bk + r) * 1024 + nof + c];
  }
  __syncthreads();
#pragma unroll
  for (int i = 0; i < 4; ++i) {
    int nl = r0 + i * 8;
    dst[(size_t)(bn + nl) * 1024 + bk + c] = (_Float16)tile[c][nl];
  }
}

__global__ void prep_bias(const float* __restrict__ bx, const float* __restrict__ by,
                          const float* __restrict__ gib, const float* __restrict__ gab,
                          float* __restrict__ b1, float* __restrict__ b2) {
  int i = blockIdx.x * 1024 + threadIdx.x;   // 0..4095
  if (i < 1024)      b1[i] = bx[i];
  else if (i < 2048) b1[i] = by[i - 1024];
  else if (i < 3072) b2[i - 2048] = gib[i - 2048];
  else               b2[i - 2048] = gab[i - 3072];
}

__global__ __launch_bounds__(256) void cvt_fp16(
    const float* __restrict__ x, _Float16* __restrict__ xh, long n4) {
  for (long i = (long)blockIdx.x * 256 + threadIdx.x; i < n4;
       i += (long)gridDim.x * 256) {
    f32x4 v = ((const f32x4*)x)[i];
    half4 h;
#pragma unroll
    for (int e = 0; e < 4; ++e) h[e] = (_Float16)v[e];
    ((half4*)xh)[i] = h;
  }
}

// ---------------- GEMM: C[M][2048] = A[M][1024] * Bt[2048][1024]^T ----------
// 256x256 tile, 8 waves (2m x 4n), per-wave 128x64, BK=64, 16 K-tiles.
// LDS: A,B each 4 units of 16KB (128 rows x 64 halfs, dbuf x 2 halves).
// Unit rows XOR-swizzled: physical_half = logical ^ ((row&7)<<3) on bits 3-5;
// staging pre-permutes the GLOBAL source block (blk = (c&7)^(r&7)) so
// global_load_lds writes linearly (rule 21: both-sides-or-neither).
// Per K-tile: 4 phases {kh,nh}: ds_read frags + stage -> BAR -> MFMA -> BAR.
// Staging of tile t+1 issued at phases 1-2; vmcnt(0) only at phase-4 end.
template <int MODE>
__global__ __launch_bounds__(512, 2) void gemm_kernel(
    const _Float16* __restrict__ A, const _Float16* __restrict__ Bt,
    const float* __restrict__ bias, const float* __restrict__ a_param,
    _Float16* __restrict__ C) {
  __shared__ _Float16 ldsA[32768];   // 64 KB: slots 0..3
  __shared__ _Float16 ldsB[32768];   // 64 KB
  int tid  = threadIdx.x;
  int lane = tid & 63;
  int wave = tid >> 6;
  int l15 = lane & 15, g = lane >> 4;

  // XCD-bijective swizzle (grid = 1024 = 8*128)
  int nb = ((int)blockIdx.x & 7) * 128 + ((int)blockIdx.x >> 3);
  int m0 = (nb >> 3) * 256;           // 128 m-tiles
  int n0 = (nb & 7) * 256;            // 8 n-tiles
  int wm = wave >> 2;                 // 0..1
  int wn = wave & 3;                  // 0..3

  // --- staging addressing: chunk c = issue*512 + tid; r=c>>3, blk=(c&7)^(r&7)
  int r0  = tid >> 3;                 // 0..63
  int blk = (tid & 7) ^ (r0 & 7);
  const _Float16* pA = A  + (size_t)(m0 + r0) * 1024 + blk * 8;
  const _Float16* pB = Bt + (size_t)(n0 + r0) * 1024 + blk * 8;
  _Float16* stA = ldsA + wave * 512;  // HW adds lane*16B
  _Float16* stB = ldsB + wave * 512;

#define STAGE_A(slot, mh, kt)                                                 \
  do {                                                                        \
    load16_lds(pA + (mh)*131072 + (kt)*64,         stA + (slot)*8192);        \
    load16_lds(pA + (mh)*131072 + 65536 + (kt)*64, stA + (slot)*8192 + 4096); \
  } while (0)
#define STAGE_B(slot, nu, kt)                                                 \
  do {                                                                        \
    load16_lds(pB + (nu)*131072 + (kt)*64,         stB + (slot)*8192);        \
    load16_lds(pB + (nu)*131072 + 65536 + (kt)*64, stB + (slot)*8192 + 4096); \
  } while (0)

  // --- fragment read offsets (halfs). Swizzle on half-index bits 3-5.
  int xorf = (l15 & 7) << 3;
  int xa0 = (g * 8) ^ xorf;           // kh = 0
  int xa1 = (32 + g * 8) ^ xorf;      // kh = 1  (== xa0 ^ 32)
  int aBase = l15 * 64;               // + unit slot later
  int bBase = ((wn & 1) * 64 + l15) * 64;
  int bUnit = wn >> 1;

  f32x4 acc[8][4];
#pragma unroll
  for (int i = 0; i < 8; ++i)
#pragma unroll
    for (int j = 0; j < 4; ++j) acc[i][j] = (f32x4){0.f, 0.f, 0.f, 0.f};

  // prologue: stage tile 0 into slots {0,1}, drain, publish.
  STAGE_A(0, 0, 0); STAGE_A(1, 1, 0);
  STAGE_B(0, 0, 0); STAGE_B(1, 1, 0);
  asm volatile("s_waitcnt vmcnt(0)" ::: "memory");
  BAR();

  half8 a[8], b0, b1;
  for (int t = 0; t < 16; ++t) {
    int db = (t & 1) << 1;            // slots of tile t
    int dn = ((t + 1) & 1) << 1;      // slots of tile t+1
    int aS = (db + wm) * 8192 + aBase;
    int bS = (db + bUnit) * 8192 + bBase;
    bool pre = (t < 15);

    // ---- phase 1: (kh0, nh0) — read A kh0 (8) + B (2); stage A0,B0(t+1)
#pragma unroll
    for (int mi = 0; mi < 8; ++mi)
      a[mi] = *(const half8*)(ldsA + aS + mi * 1024 + xa0);
    b0 = *(const half8*)(ldsB + bS + xa0);
    b1 = *(const half8*)(ldsB + bS + 1024 + xa0);
    if (pre) { STAGE_A(dn, 0, t + 1); STAGE_B(dn, 0, t + 1); }
    BAR();
    __builtin_amdgcn_s_setprio(1);
#pragma unroll
    for (int mi = 0; mi < 8; ++mi) acc[mi][0] = MFMA16(a[mi], b0, acc[mi][0]);
#pragma unroll
    for (int mi = 0; mi < 8; ++mi) acc[mi][1] = MFMA16(a[mi], b1, acc[mi][1]);
    __builtin_amdgcn_s_setprio(0);
    BAR();

    // ---- phase 2: (kh0, nh1) — read B (2); stage A1,B1(t+1)
    b0 = *(const half8*)(ldsB + bS + 2048 + xa0);
    b1 = *(const half8*)(ldsB + bS + 3072 + xa0);
    if (pre) { STAGE_A(dn + 1, 1, t + 1); STAGE_B(dn + 1, 1, t + 1); }
    BAR();
    __builtin_amdgcn_s_setprio(1);
#pragma unroll
    for (int mi = 0; mi < 8; ++mi) acc[mi][2] = MFMA16(a[mi], b0, acc[mi][2]);
#pragma unroll
    for (int mi = 0; mi < 8; ++mi) acc[mi][3] = MFMA16(a[mi], b1, acc[mi][3]);
    __builtin_amdgcn_s_setprio(0);
    BAR();

    // ---- phase 3: (kh1, nh0) — read A kh1 (8) + B (2)
#pragma unroll
    for (int mi = 0; mi < 8; ++mi)
      a[mi] = *(const half8*)(ldsA + aS + mi * 1024 + xa1);
    b0 = *(const half8*)(ldsB + bS + xa1);
    b1 = *(const half8*)(ldsB + bS + 1024 + xa1);
    BAR();
    __builtin_amdgcn_s_setprio(1);
#pragma unroll
    for (int mi = 0; mi < 8; ++mi) acc[mi][0] = MFMA16(a[mi], b0, acc[mi][0]);
#pragma unroll
    for (int mi = 0; mi < 8; ++mi) acc[mi][1] = MFMA16(a[mi], b1, acc[mi][1]);
    __builtin_amdgcn_s_setprio(0);
    BAR();

    // ---- phase 4: (kh1, nh1) — read B (2); vmcnt(0) then publish t+1
    b0 = *(const half8*)(ldsB + bS + 2048 + xa1);
    b1 = *(const half8*)(ldsB + bS + 3072 + xa1);
    BAR();
    __builtin_amdgcn_s_setprio(1);
#pragma unroll
    for (int mi = 0; mi < 8; ++mi) acc[mi][2] = MFMA16(a[mi], b0, acc[mi][2]);
#pragma unroll
    for (int mi = 0; mi < 8; ++mi) acc[mi][3] = MFMA16(a[mi], b1, acc[mi][3]);
    __builtin_amdgcn_s_setprio(0);
    asm volatile("s_waitcnt vmcnt(0)" ::: "memory");   // t+1 slots complete
    BAR();
  }

  // epilogue: C/D layout col=lane&15, row=(lane>>4)*4+p
  int   gn[4];
  float bs[4], sp[4];
#pragma unroll
  for (int nj = 0; nj < 4; ++nj) {
    gn[nj] = n0 + wn * 64 + nj * 16 + l15;
    bs[nj] = bias[gn[nj]];
    sp[nj] = 0.f;
    if (MODE == 1 && gn[nj] >= 1024)
      sp[nj] = log1pf(expf(a_param[gn[nj] - 1024]));   // softplus
  }
#pragma unroll
  for (int mi = 0; mi < 8; ++mi) {
#pragma unroll
    for (int p = 0; p < 4; ++p) {
      int gm = m0 + wm * 128 + mi * 16 + g * 4 + p;
      size_t rowb = (size_t)gm * 2048;
#pragma unroll
      for (int nj = 0; nj < 4; ++nj) {
        float v = acc[mi][nj][p] + bs[nj];
        if (MODE == 1) {
          float s = 1.f / (1.f + expf(-v));
          if (gn[nj] < 1024) {
            v = s;                          // gate_x
          } else {
            float av = expf(-8.f * s * sp[nj]);
            if ((gm & (T_ - 1)) == 0) av = 0.f;   // t == 0
            v = av;
          }
        }
        C[rowb + gn[nj]] = (_Float16)v;
      }
    }
  }
#undef STAGE_A
#undef STAGE_B
}

// ---------------- conv: x2 = sum_j cw[3-j]*x1[t-j] + cb ---------------------
__global__ __launch_bounds__(256) void conv_kernel(
    const _Float16* __restrict__ g1, const float* __restrict__ cw,
    const float* __restrict__ cb, _Float16* __restrict__ x2) {
  int idx = blockIdx.x * 256 + threadIdx.x;   // over M_*H_/8
  int m  = idx >> 7;
  int hb = (idx & 127) * 8;
  int t  = m & (T_ - 1);
  float acc[8];
#pragma unroll
  for (int e = 0; e < 8; ++e) acc[e] = cb[hb + e];
#pragma unroll
  for (int j = 0; j < 4; ++j) {
    if (t >= j) {
      half8 xv = *(const half8*)&g1[(size_t)(m - j) * 2048 + hb];
      const float* w = &cw[(3 - j) * 1024 + hb];
#pragma unroll
      for (int e = 0; e < 8; ++e) acc[e] += w[e] * (float)xv[e];
    }
  }
  half8 o;
#pragma unroll
  for (int e = 0; e < 8; ++e) o[e] = (_Float16)acc[e];
  *(half8*)&x2[(size_t)m * 1024 + hb] = o;
}

// ---------------- scan pass 1: per-chunk (prod a, local h) ------------------
__global__ __launch_bounds__(128) void scan1_kernel(
    const _Float16* __restrict__ g2, const _Float16* __restrict__ x2,
    float* __restrict__ cA, float* __restrict__ cH) {
  int bid = blockIdx.x;          // b*NC_ + c
  int b = bid >> 7, c = bid & 127;
  int h0 = threadIdx.x * 8;
  float A[8], Hh[8];
#pragma unroll
  for (int e = 0; e < 8; ++e) { A[e] = 1.f; Hh[e] = 0.f; }
  size_t mbase = (size_t)b * T_ + (size_t)c * CL_;
  for (int i = 0; i < CL_; ++i) {
    size_t m = mbase + i;
    half8 gx = *(const half8*)&g2[m * 2048 + h0];
    half8 av = *(const half8*)&g2[m * 2048 + 1024 + h0];
    half8 xv = *(const half8*)&x2[m * 1024 + h0];
#pragma unroll
    for (int e = 0; e < 8; ++e) {
      float a = (float)av[e];
      float mult = sqrtf(fmaxf(1.f - a * a, 0.f));
      float nx = (float)gx[e] * (float)xv[e] * mult;
      A[e] *= a;
      Hh[e] = nx + a * Hh[e];
    }
  }
  size_t o = (size_t)bid * 1024 + h0;
#pragma unroll
  for (int e = 0; e < 8; ++e) { cA[o + e] = A[e]; cH[o + e] = Hh[e]; }
}

// ---------------- scan pass 2: carries across chunks ------------------------
__global__ void scanmid_kernel(const float* __restrict__ cA,
                               const float* __restrict__ cH,
                               float* __restrict__ carry) {
  int gidx = blockIdx.x * 256 + threadIdx.x;  // 8192 = B_*H_
  int b = gidx >> 10, h = gidx & 1023;
  float run = 0.f;
  for (int c = 0; c < NC_; ++c) {
    size_t o = ((size_t)(b * NC_ + c)) * 1024 + h;
    carry[o] = run;
    run = cH[o] + cA[o] * run;
  }
}

// ---------------- scan pass 3: h, out = h*gelu(u), hn -----------------------
__global__ __launch_bounds__(128) void scan2_kernel(
    const _Float16* __restrict__ g2, const _Float16* __restrict__ x2,
    const _Float16* __restrict__ g1, const float* __restrict__ carry,
    float* __restrict__ outO, float* __restrict__ outH,
    float* __restrict__ outHn) {
  int bid = blockIdx.x;
  int b = bid >> 7, c = bid & 127;
  int h0 = threadIdx.x * 8;
  float Hh[8];
  {
    size_t o = (size_t)bid * 1024 + h0;
#pragma unroll
    for (int e = 0; e < 8; ++e) Hh[e] = carry[o + e];
  }
  size_t mbase = (size_t)b * T_ + (size_t)c * CL_;
  for (int i = 0; i < CL_; ++i) {
    size_t m = mbase + i;
    half8 gx = *(const half8*)&g2[m * 2048 + h0];
    half8 av = *(const half8*)&g2[m * 2048 + 1024 + h0];
    half8 xv = *(const half8*)&x2[m * 1024 + h0];
    half8 uv = *(const half8*)&g1[m * 2048 + 1024 + h0];
    f32x4 hO[2], oO[2];
#pragma unroll
    for (int e = 0; e < 8; ++e) {
      float a = (float)av[e];
      float mult = sqrtf(fmaxf(1.f - a * a, 0.f));
      float nx = (float)gx[e] * (float)xv[e] * mult;
      float v = nx + a * Hh[e];
      Hh[e] = v;
      float u = (float)uv[e];
      float y = 0.5f * u * (1.f + erff(u * 0.70710678118654752f));  // exact gelu
      hO[e >> 2][e & 3] = v;
      oO[e >> 2][e & 3] = v * y;
    }
    size_t ob = m * 1024 + h0;
    *(f32x4*)&outH[ob]     = hO[0];
    *(f32x4*)&outH[ob + 4] = hO[1];
    *(f32x4*)&outO[ob]     = oO[0];
    *(f32x4*)&outO[ob + 4] = oO[1];
  }
  if (c == NC_ - 1) {
    size_t o = (size_t)b * 1024 + h0;
#pragma unroll
    for (int e = 0; e < 8; ++e) outHn[o + e] = Hh[e];
  }
}

// ---------------------------------------------------------------------------
extern "C" void kernel_launch(void* const* d_in, const int* in_sizes, int n_in,
                              void* d_out, int out_size, void* d_ws,
                              size_t ws_size, hipStream_t stream) {
  const float* x   = (const float*)d_in[0];
  const float* wx  = (const float*)d_in[1];
  const float* bx  = (const float*)d_in[2];
  const float* wy  = (const float*)d_in[3];
  const float* by  = (const float*)d_in[4];
  const float* cw  = (const float*)d_in[5];
  const float* cb  = (const float*)d_in[6];
  const float* giw = (const float*)d_in[7];
  const float* gib = (const float*)d_in[8];
  const float* gaw = (const float*)d_in[9];
  const float* gab = (const float*)d_in[10];
  const float* ap  = (const float*)d_in[11];

  char* ws = (char*)d_ws;
  size_t off = 0;
  auto alloc = [&](size_t bytes) {
    char* p = ws + off;
    off += (bytes + 255) & ~(size_t)255;
    return p;
  };
  _Float16* wT1 = (_Float16*)alloc((size_t)2048 * 1024 * 2);  // [n][k] fp16
  _Float16* wT2 = (_Float16*)alloc((size_t)2048 * 1024 * 2);
  float*    b1  = (float*)alloc(2048 * 4);
  float*    b2  = (float*)alloc(2048 * 4);
  _Float16* xh  = (_Float16*)alloc((size_t)M_ * 1024 * 2);  // x fp16; aliased
  _Float16* g2e = (_Float16*)alloc((size_t)M_ * 1024 * 2);  // extension
  (void)g2e;
  _Float16* g1o = (_Float16*)alloc((size_t)M_ * 2048 * 2);  // [x1 | u]
  _Float16* x2h = (_Float16*)alloc((size_t)M_ * 1024 * 2);  // x2
  float* cA  = (float*)alloc((size_t)B_ * NC_ * 1024 * 4);
  float* cH  = (float*)alloc((size_t)B_ * NC_ * 1024 * 4);
  float* cin = (float*)alloc((size_t)B_ * NC_ * 1024 * 4);
  _Float16* g2o = xh;  // [gx | a], 134MB spanning xh+g2e (xh dead by then)

  float* oO  = (float*)d_out;
  float* oH  = oO + (size_t)M_ * 1024;
  float* oHn = oO + (size_t)2 * M_ * 1024;

  transpose_cvt<<<dim3(64, 32), 256, 0, stream>>>(wx, wy, wT1);
  transpose_cvt<<<dim3(64, 32), 256, 0, stream>>>(giw, gaw, wT2);
  prep_bias<<<4, 1024, 0, stream>>>(bx, by, gib, gab, b1, b2);
  cvt_fp16<<<2048, 256, 0, stream>>>(x, xh, (long)M_ * 1024 / 4);

  gemm_kernel<0><<<1024, 512, 0, stream>>>(xh, wT1, b1, nullptr, g1o);
  conv_kernel<<<16384, 256, 0, stream>>>(g1o, cw, cb, x2h);
  gemm_kernel<1><<<1024, 512, 0, stream>>>(x2h, wT2, b2, ap, g2o);

  scan1_kernel<<<B_ * NC_, 128, 0, stream>>>(g2o, x2h, cA, cH);
  scanmid_kernel<<<32, 256, 0, stream>>>(cA, cH, cin);
  scan2_kernel<<<B_ * NC_, 128, 0, stream>>>(g2o, x2h, g1o, cin, oO, oH, oHn);
}